// Round 3
// baseline (192.000 us; speedup 1.0000x reference)
//
#include <hip/hip_runtime.h>
#include <hip/hip_bf16.h>
#include <stdint.h>

#define B_ 64
#define N_ 1024
#define D_ 128

typedef __attribute__((ext_vector_type(8))) short bf16x8;
typedef __attribute__((ext_vector_type(4))) float f32x4;

__device__ __forceinline__ unsigned short f2bf(float f) {
    union { float f; uint32_t u; } v; v.f = f;
    uint32_t u = v.u;
    return (unsigned short)((u + 0x7FFFu + ((u >> 16) & 1u)) >> 16);
}

// ---------------------------------------------------------------------------
// Kernel 1: W (f32 [k=128][d=128]) -> bf16 W^T [d][k], for Wq/Wk/Wv.
__global__ __launch_bounds__(256) void wtrans_kernel(
    const float* __restrict__ Wq, const float* __restrict__ Wk,
    const float* __restrict__ Wv, unsigned short* __restrict__ wt)
{
    int p = blockIdx.x >> 4;
    int seg = blockIdx.x & 15;
    const float* W = (p == 0) ? Wq : (p == 1) ? Wk : Wv;
    unsigned short* dst = wt + p * (D_ * D_);
    for (int i = 0; i < 4; ++i) {
        int idx = seg * 1024 + i * 256 + (int)threadIdx.x;
        int k = idx >> 7, d = idx & 127;
        dst[d * D_ + k] = f2bf(W[idx]);
    }
}

// ---------------------------------------------------------------------------
// Kernel 2: QKV projection. 64 rows of x per block. q,k stored row-major bf16;
// v stored TRANSPOSED (V^T [B][D][N] bf16) via LDS so attention needs no
// transpose. 1/sqrt(D) folded into q.
__global__ __launch_bounds__(256) void proj_kernel(
    const float* __restrict__ x,
    const unsigned short* __restrict__ wtg,
    const float* __restrict__ bq, const float* __restrict__ bk,
    const float* __restrict__ bv,
    unsigned short* __restrict__ qo, unsigned short* __restrict__ ko,
    unsigned short* __restrict__ vto)
{
    __shared__ alignas(16) unsigned short xs[64 * 136];   // +8 pad
    __shared__ alignas(16) unsigned short ws[128 * 136];  // +8 pad (reused as V^T buf)
    const int tid = threadIdx.x;
    const int row0 = blockIdx.x * 64;

    // stage x tile f32->bf16 (coalesced float4 loads)
    for (int it = 0; it < 8; ++it) {
        int idx4 = it * 256 + tid;          // 2048 float4 = 64x128
        int r = idx4 >> 5, c4 = (idx4 & 31) * 4;
        const float4 v = *(const float4*)&x[(size_t)(row0 + r) * D_ + c4];
        unsigned short tmp[4] = { f2bf(v.x), f2bf(v.y), f2bf(v.z), f2bf(v.w) };
        *(uint2*)&xs[r * 136 + c4] = *(uint2*)tmp;
    }

    const int wave = tid >> 6, lane = tid & 63;
    const int lr = lane & 15, lg = lane >> 4;
    const f32x4 zero4 = {0.f, 0.f, 0.f, 0.f};

    for (int p = 0; p < 3; ++p) {
        __syncthreads();   // xs ready (p=0) / prior ws reads done (p>0)
        const unsigned short* wsrc = wtg + p * (D_ * D_);
        for (int it = 0; it < 8; ++it) {
            int idx8 = it * 256 + tid;      // 2048 x 8 bf16 = 128x128
            int r = idx8 >> 4, c8 = (idx8 & 15) * 8;
            *(bf16x8*)&ws[r * 136 + c8] = *(const bf16x8*)&wsrc[idx8 * 8];
        }
        __syncthreads();

        bf16x8 a[4];
        for (int kk = 0; kk < 4; ++kk)
            a[kk] = *(const bf16x8*)&xs[(wave * 16 + lr) * 136 + kk * 32 + lg * 8];
        f32x4 acc[8];
        for (int nt = 0; nt < 8; ++nt) acc[nt] = zero4;
        for (int kk = 0; kk < 4; ++kk)
            for (int nt = 0; nt < 8; ++nt) {
                bf16x8 bfr = *(const bf16x8*)&ws[(nt * 16 + lr) * 136 + kk * 32 + lg * 8];
                acc[nt] = __builtin_amdgcn_mfma_f32_16x16x32_bf16(a[kk], bfr, acc[nt], 0, 0, 0);
            }

        if (p < 2) {
            const float* bias = (p == 0) ? bq : bk;
            unsigned short* outp = (p == 0) ? qo : ko;
            const float sc = (p == 0) ? 0.08838834764831845f : 1.0f; // 1/sqrt(128) into q
            for (int nt = 0; nt < 8; ++nt) {
                int d = nt * 16 + lr;
                float bb = bias[d];
                for (int r = 0; r < 4; ++r) {
                    int grow = row0 + wave * 16 + lg * 4 + r;  // C/D: row=(lane>>4)*4+reg
                    outp[(size_t)grow * D_ + d] = f2bf((acc[nt][r] + bb) * sc);
                }
            }
        } else {
            // V: bias, then transpose via LDS (reuse ws as [128][72]) and store V^T
            __syncthreads();  // everyone done reading ws (W^T)
            for (int nt = 0; nt < 8; ++nt) {
                int d = nt * 16 + lr;
                float bb = bv[d];
                for (int r = 0; r < 4; ++r)
                    ws[d * 72 + wave * 16 + lg * 4 + r] = f2bf(acc[nt][r] + bb);
            }
            __syncthreads();
            const int b = row0 >> 10, n0 = row0 & 1023;
            unsigned short* dst = vto + ((size_t)b * D_) * N_ + n0;
            for (int it = 0; it < 4; ++it) {
                int idx = it * 256 + tid;           // 1024 chunks of 8 bf16 = 128x64
                int d = idx >> 3, c8 = (idx & 7) * 8;
                *(bf16x8*)&dst[(size_t)d * N_ + c8] = *(const bf16x8*)&ws[d * 72 + c8];
            }
        }
    }
}

// ---------------------------------------------------------------------------
// Kernel 3: flash attention, wave-independent. No barriers, no K/V LDS staging
// (K/V are L2-resident per batch; fragments loaded directly from global).
// Block = 4 waves x 16 q-rows. Mapping keeps b%8 == blockid%8 (XCD affinity)
// and launches high-qt (longest) tiles first.
__global__ __launch_bounds__(256, 4) void attn_kernel(
    const unsigned short* __restrict__ qg, const unsigned short* __restrict__ kg,
    const unsigned short* __restrict__ vtg, const int* __restrict__ valid_lens,
    float* __restrict__ out)
{
    __shared__ alignas(16) unsigned short ps[4][16 * 72]; // per-wave P tile

    const int id = blockIdx.x;
    const int x_ = id & 7, g = id >> 3;
    const int qt = 15 - (g & 15);
    const int b = ((g >> 4) << 3) + x_;
    const int L = valid_lens[b];
    const int wave = threadIdx.x >> 6, lane = threadIdx.x & 63;
    const int lr = lane & 15, lg = lane >> 4;
    const int qrow0 = qt * 64 + wave * 16;      // this wave's 16 q rows
    float* outw = out + ((size_t)b * N_ + qrow0) * D_;

    if (qrow0 >= L) {   // fully masked rows -> zeros (per-wave, no barrier)
        for (int it = 0; it < 8; ++it) {
            int idx4 = it * 64 + lane;          // 512 float4 = 16x128
            int r = idx4 >> 5, c4 = (idx4 & 31) * 4;
            float4 z; z.x = z.y = z.z = z.w = 0.f;
            *(float4*)&outw[(size_t)r * D_ + c4] = z;
        }
        return;
    }

    const unsigned short* kgb = kg + (size_t)b * N_ * D_;
    const unsigned short* vtb = vtg + (size_t)b * D_ * N_;
    const f32x4 zero4 = {0.f, 0.f, 0.f, 0.f};

    // Q fragments (scale folded in at projection)
    bf16x8 aq[4];
    {
        const unsigned short* qrow = qg + ((size_t)b * N_ + qrow0 + lr) * D_;
        for (int kk = 0; kk < 4; ++kk)
            aq[kk] = *(const bf16x8*)&qrow[kk * 32 + lg * 8];
    }

    f32x4 oacc[8];
    for (int i = 0; i < 8; ++i) oacc[i] = zero4;
    float mrun[4], lrun[4];
    for (int r = 0; r < 4; ++r) { mrun[r] = -1e30f; lrun[r] = 0.f; }

    unsigned short* pw = ps[wave];
    const int ntiles = (L + 63) >> 6;
    for (int t = 0; t < ntiles; ++t) {
        const int kv0 = t * 64;

        // S = Q K^T  (K-fragments straight from global/L2)
        f32x4 s[4];
        const unsigned short* kt = kgb + (size_t)kv0 * D_ + lr * D_ + lg * 8;
        for (int nt = 0; nt < 4; ++nt) {
            s[nt] = zero4;
            for (int kk = 0; kk < 4; ++kk) {
                bf16x8 bk_ = *(const bf16x8*)&kt[nt * (16 * D_) + kk * 32];
                s[nt] = __builtin_amdgcn_mfma_f32_16x16x32_bf16(aq[kk], bk_, s[nt], 0, 0, 0);
            }
        }
        // column mask (j >= L)
        for (int nt = 0; nt < 4; ++nt) {
            int j = kv0 + nt * 16 + lr;
            if (j >= L) for (int r = 0; r < 4; ++r) s[nt][r] = -1e30f;
        }
        // online softmax over kv (16-lane groups hold a full row)
        float pm[4];
        for (int r = 0; r < 4; ++r)
            pm[r] = fmaxf(fmaxf(s[0][r], s[1][r]), fmaxf(s[2][r], s[3][r]));
        for (int off = 1; off < 16; off <<= 1)
            for (int r = 0; r < 4; ++r)
                pm[r] = fmaxf(pm[r], __shfl_xor(pm[r], off));
        float alpha[4];
        for (int r = 0; r < 4; ++r) {
            float mn = fmaxf(mrun[r], pm[r]);
            alpha[r] = __expf(mrun[r] - mn);
            mrun[r] = mn;
        }
        float p[4][4], rs[4];
        for (int r = 0; r < 4; ++r) rs[r] = 0.f;
        for (int nt = 0; nt < 4; ++nt)
            for (int r = 0; r < 4; ++r) {
                float e = __expf(s[nt][r] - mrun[r]);
                p[nt][r] = e;
                rs[r] += e;
            }
        for (int off = 1; off < 16; off <<= 1)
            for (int r = 0; r < 4; ++r)
                rs[r] += __shfl_xor(rs[r], off);
        for (int r = 0; r < 4; ++r) lrun[r] = lrun[r] * alpha[r] + rs[r];
        for (int nt = 0; nt < 8; ++nt)
            for (int r = 0; r < 4; ++r)
                oacc[nt][r] *= alpha[r];

        // P -> wave-private LDS (bf16) -> A-fragments (same-wave RAW, in-order)
        for (int nt = 0; nt < 4; ++nt)
            for (int r = 0; r < 4; ++r)
                pw[(lg * 4 + r) * 72 + nt * 16 + lr] = f2bf(p[nt][r]);

        // O += P V   (V^T fragments straight from global/L2)
        const unsigned short* vt0 = vtb + (size_t)lr * N_ + kv0 + lg * 8;
        for (int kk = 0; kk < 2; ++kk) {
            bf16x8 ap = *(const bf16x8*)&pw[lr * 72 + kk * 32 + lg * 8];
            for (int nt = 0; nt < 8; ++nt) {
                bf16x8 bv_ = *(const bf16x8*)&vt0[(size_t)(nt * 16) * N_ + kk * 32];
                oacc[nt] = __builtin_amdgcn_mfma_f32_16x16x32_bf16(ap, bv_, oacc[nt], 0, 0, 0);
            }
        }
    }

    // epilogue: divide by l, zero rows >= L
    for (int r = 0; r < 4; ++r) {
        int qrow = qrow0 + lg * 4 + r;
        float inv = (qrow < L) ? 1.0f / lrun[r] : 0.0f;
        for (int nt = 0; nt < 8; ++nt) {
            int d = nt * 16 + lr;
            outw[(size_t)(lg * 4 + r) * D_ + d] = oacc[nt][r] * inv;
        }
    }
}

// ---------------------------------------------------------------------------
extern "C" void kernel_launch(void* const* d_in, const int* in_sizes, int n_in,
                              void* d_out, int out_size, void* d_ws, size_t ws_size,
                              hipStream_t stream) {
    const float* x    = (const float*)d_in[0];
    const int*   vlen = (const int*)d_in[1];
    const float* Wq   = (const float*)d_in[2];
    const float* bq   = (const float*)d_in[3];
    const float* Wk   = (const float*)d_in[4];
    const float* bk   = (const float*)d_in[5];
    const float* Wv   = (const float*)d_in[6];
    const float* bv   = (const float*)d_in[7];
    float* out = (float*)d_out;

    // ws layout: [W^T bf16 x3 | q bf16 | k bf16 | v^T bf16]
    unsigned short* wt  = (unsigned short*)d_ws;                  // 3*128*128
    unsigned short* qws = (unsigned short*)((char*)d_ws + 98304);
    unsigned short* kws = qws + (size_t)B_ * N_ * D_;
    unsigned short* vtws = kws + (size_t)B_ * N_ * D_;

    wtrans_kernel<<<48, 256, 0, stream>>>(Wq, Wk, Wv, wt);
    proj_kernel<<<(B_ * N_) / 64, 256, 0, stream>>>(x, wt, bq, bk, bv, qws, kws, vtws);
    attn_kernel<<<1024, 256, 0, stream>>>(qws, kws, vtws, vlen, out);
}